// Round 2
// baseline (194.062 us; speedup 1.0000x reference)
//
#include <hip/hip_runtime.h>
#include <math.h>

#define NB   16
#define DIN  1024
#define TT   4096
#define DC   8
#define NK   1024

// K1 geometry: float2 per thread, 256 threads, t-tile 512, d-chunk 256
#define DCH   256
#define NDC   (DIN/DCH)     // 4
#define TILE1 512
#define NT1   (TT/TILE1)    // 8

// K2 geometry: 512 threads (2-way k split), t-tile 256
#define TILE2 256
#define NT2   (TT/TILE2)    // 16

// K3 geometry: float4 per thread, 256 threads, t-tile 1024, o-chunk 128
#define OCH   128
#define NOC   (DIN/OCH)     // 8
#define TILE3 1024
#define NT3   (TT/TILE3)    // 4

// d_out offsets (floats), in reference return order
#define OFF_CL  ((size_t)NB*DIN*TT)
#define OFF_CB  (OFF_CL + NB)
#define OFF_IDX (OFF_CB + NB)
#define OFF_ZE  (OFF_IDX + (size_t)NB*TT)

// ---------------- K1: in_proj partial sums (d-split x4, float2 t-vector) ----------------
__global__ __launch_bounds__(256) void vq_k1_inproj(const float* __restrict__ z,
    const float* __restrict__ in_w, float* __restrict__ P)
{
  __shared__ float wt[DCH*DC];
  const int tid = threadIdx.x;
  const int tt = blockIdx.x, b = blockIdx.y, dc = blockIdx.z;
  const int dbase = dc*DCH;
  #pragma unroll
  for (int o = 0; o < DC; ++o)
    wt[tid*DC + o] = in_w[o*DIN + dbase + tid];
  __syncthreads();
  const int t = tt*TILE1 + tid*2;
  const float* zp = z + ((size_t)b*DIN + dbase)*TT + t;
  float ax[DC], ay[DC];
  #pragma unroll
  for (int o = 0; o < DC; ++o) { ax[o] = 0.f; ay[o] = 0.f; }
  #pragma unroll 8
  for (int d = 0; d < DCH; ++d) {
    const float2 v = *(const float2*)&zp[(size_t)d*TT];
    const float4 w0 = *(const float4*)&wt[d*DC];
    const float4 w1 = *(const float4*)&wt[d*DC+4];
    ax[0] = fmaf(v.x, w0.x, ax[0]);  ay[0] = fmaf(v.y, w0.x, ay[0]);
    ax[1] = fmaf(v.x, w0.y, ax[1]);  ay[1] = fmaf(v.y, w0.y, ay[1]);
    ax[2] = fmaf(v.x, w0.z, ax[2]);  ay[2] = fmaf(v.y, w0.z, ay[2]);
    ax[3] = fmaf(v.x, w0.w, ax[3]);  ay[3] = fmaf(v.y, w0.w, ay[3]);
    ax[4] = fmaf(v.x, w1.x, ax[4]);  ay[4] = fmaf(v.y, w1.x, ay[4]);
    ax[5] = fmaf(v.x, w1.y, ax[5]);  ay[5] = fmaf(v.y, w1.y, ay[5]);
    ax[6] = fmaf(v.x, w1.z, ax[6]);  ay[6] = fmaf(v.y, w1.z, ay[6]);
    ax[7] = fmaf(v.x, w1.w, ax[7]);  ay[7] = fmaf(v.y, w1.w, ay[7]);
  }
  float* pp = P + ((size_t)(dc*NB + b)*DC)*TT + t;
  #pragma unroll
  for (int o = 0; o < DC; ++o)
    *(float2*)&pp[(size_t)o*TT] = make_float2(ax[o], ay[o]);
}

// ---------------- K2: combine + VQ search (2-way k-split) + rotation trick ----------------
__global__ __launch_bounds__(512) void vq_k2_search(const float* __restrict__ P,
    const float* __restrict__ in_b, const float* __restrict__ cbk,
    float* __restrict__ dout, float* __restrict__ zq, float* __restrict__ lpart)
{
  __shared__ float cn[NK*DC];       // 32 KB normalized codebook
  __shared__ float cn2[NK];         // 4 KB
  __shared__ float en_s[TILE2*DC];  // 8 KB normalized e, [t][c]
  __shared__ float en2_s[TILE2];    // 1 KB
  __shared__ float rd[512];
  __shared__ int   rk[512];
  __shared__ float lred[TILE2];
  const int tid = threadIdx.x;
  const int tt = blockIdx.x, b = blockIdx.y;
  const int tl = tid & (TILE2-1);

  // stage + normalize codebook (x / max(||x||,1e-12))
  for (int k = tid; k < NK; k += 512) {
    float c[DC];
    const float4 c0 = *(const float4*)&cbk[k*DC];
    const float4 c1 = *(const float4*)&cbk[k*DC+4];
    c[0]=c0.x; c[1]=c0.y; c[2]=c0.z; c[3]=c0.w;
    c[4]=c1.x; c[5]=c1.y; c[6]=c1.z; c[7]=c1.w;
    float ss = 0.f;
    #pragma unroll
    for (int i = 0; i < DC; ++i) ss = fmaf(c[i], c[i], ss);
    const float den = fmaxf(sqrtf(ss), 1e-12f);
    float s2 = 0.f;
    #pragma unroll
    for (int i = 0; i < DC; ++i) { const float v = c[i]/den; cn[k*DC+i] = v; s2 = fmaf(v, v, s2); }
    cn2[k] = s2;
  }

  const int t = tt*TILE2 + tl;
  float e[DC], en[DC];
  float ne = 0.f, my_en2 = 0.f;

  // phase A: combine partials, write z_e, normalize (threads 0..255 only)
  if (tid < TILE2) {
    const float* pp = P + ((size_t)b*DC)*TT + t;
    const size_t cs = (size_t)NB*DC*TT;
    #pragma unroll
    for (int o = 0; o < DC; ++o) {
      float s = pp[(size_t)o*TT];
      s += pp[cs   + (size_t)o*TT];
      s += pp[2*cs + (size_t)o*TT];
      s += pp[3*cs + (size_t)o*TT];
      e[o] = s + in_b[o];
    }
    #pragma unroll
    for (int o = 0; o < DC; ++o)
      dout[OFF_ZE + ((size_t)b*DC + o)*TT + t] = e[o];
    float se = 0.f;
    #pragma unroll
    for (int i = 0; i < DC; ++i) se = fmaf(e[i], e[i], se);
    ne = sqrtf(se);
    const float dene = fmaxf(ne, 1e-12f);
    float s2 = 0.f;
    #pragma unroll
    for (int i = 0; i < DC; ++i) { en[i] = e[i]/dene; s2 = fmaf(en[i], en[i], s2); en_s[tl*DC + i] = en[i]; }
    my_en2 = s2;
    en2_s[tl] = s2;
  }
  __syncthreads();

  // phase B: all 512 threads scan half the codebook for their t
  {
    float me[DC];
    #pragma unroll
    for (int i = 0; i < DC; ++i) me[i] = en_s[tl*DC + i];
    const float me2 = en2_s[tl];
    const int k0 = (tid >> 8) * (NK/2);
    float bestd = 3.4e38f; int bk = k0;
    #pragma unroll 4
    for (int k = k0; k < k0 + NK/2; ++k) {
      const float4 a0 = *(const float4*)&cn[k*DC];
      const float4 a1 = *(const float4*)&cn[k*DC+4];
      float dacc = me[0]*a0.x;
      dacc = fmaf(me[1], a0.y, dacc);
      dacc = fmaf(me[2], a0.z, dacc);
      dacc = fmaf(me[3], a0.w, dacc);
      dacc = fmaf(me[4], a1.x, dacc);
      dacc = fmaf(me[5], a1.y, dacc);
      dacc = fmaf(me[6], a1.z, dacc);
      dacc = fmaf(me[7], a1.w, dacc);
      const float dist = (me2 - 2.0f*dacc) + cn2[k];
      if (dist < bestd) { bestd = dist; bk = k; }
    }
    rd[tid] = bestd; rk[tid] = bk;
  }
  __syncthreads();

  // phase C: merge halves (lower k wins ties -> first occurrence), rotation trick
  float cl = 0.f;
  if (tid < TILE2) {
    const float d0 = rd[tid], d1 = rd[tid + TILE2];
    const int bk = (d1 < d0) ? rk[tid + TILE2] : rk[tid];
    dout[OFF_IDX + (size_t)b*TT + t] = (float)bk;

    float q[DC];
    const float4 q0 = *(const float4*)&cbk[bk*DC];
    const float4 q1 = *(const float4*)&cbk[bk*DC+4];
    q[0]=q0.x; q[1]=q0.y; q[2]=q0.z; q[3]=q0.w;
    q[4]=q1.x; q[5]=q1.y; q[6]=q1.z; q[7]=q1.w;

    #pragma unroll
    for (int i = 0; i < DC; ++i) { const float d = e[i]-q[i]; cl = fmaf(d, d, cl); }

    float sq = 0.f;
    #pragma unroll
    for (int i = 0; i < DC; ++i) sq = fmaf(q[i], q[i], sq);
    const float nq = sqrtf(sq);
    const float denq = fmaxf(nq, 1e-12f);
    float qn[DC], rr[DC];
    float sr = 0.f;
    #pragma unroll
    for (int i = 0; i < DC; ++i) { qn[i] = q[i]/denq; rr[i] = en[i]+qn[i]; sr = fmaf(rr[i], rr[i], sr); }
    const float denr = fmaxf(sqrtf(sr), 1e-12f);
    float r_[DC];
    float rdz = 0.f, edz = 0.f;
    #pragma unroll
    for (int i = 0; i < DC; ++i) { r_[i] = rr[i]/denr; rdz = fmaf(r_[i], e[i], rdz); edz = fmaf(en[i], e[i], edz); }
    const float scal = nq / fmaxf(ne, 1e-8f);
    #pragma unroll
    for (int i = 0; i < DC; ++i) {
      const float v = scal * ((e[i] - 2.0f*r_[i]*rdz) + 2.0f*qn[i]*edz);
      zq[((size_t)b*DC + i)*TT + t] = v;
    }
    lred[tl] = cl;
  }
  __syncthreads();
  for (int s = TILE2/2; s > 0; s >>= 1) {
    if (tid < s) lred[tid] += lred[tid + s];
    __syncthreads();
  }
  if (tid == 0) lpart[b*NT2 + tt] = lred[0];
}

// ---------------- K3: out_proj (o-split x8, float4 t-vector) ----------------
__global__ __launch_bounds__(256) void vq_k3_outproj(const float* __restrict__ zq,
    const float* __restrict__ out_w, const float* __restrict__ out_b,
    float* __restrict__ dout)
{
  __shared__ float wo[OCH*DC];   // 1024 floats
  __shared__ float ob[OCH];
  const int tid = threadIdx.x;
  const int tt = blockIdx.x, b = blockIdx.y, oc = blockIdx.z;
  const int obase = oc*OCH;
  *(float4*)&wo[tid*4] = *(const float4*)&out_w[obase*DC + tid*4];
  if (tid < OCH) ob[tid] = out_b[obase + tid];
  __syncthreads();
  const int t = tt*TILE3 + tid*4;
  float z0[DC], z1[DC], z2[DC], z3[DC];
  #pragma unroll
  for (int c = 0; c < DC; ++c) {
    const float4 v = *(const float4*)&zq[((size_t)b*DC + c)*TT + t];
    z0[c]=v.x; z1[c]=v.y; z2[c]=v.z; z3[c]=v.w;
  }
  float* op = dout + ((size_t)b*DIN + obase)*TT + t;
  #pragma unroll 2
  for (int o = 0; o < OCH; ++o) {
    const float4 w0 = *(const float4*)&wo[o*DC];
    const float4 w1 = *(const float4*)&wo[o*DC+4];
    const float bv = ob[o];
    float s0 = bv, s1 = bv, s2 = bv, s3 = bv;
    s0 = fmaf(z0[0], w0.x, s0); s1 = fmaf(z1[0], w0.x, s1); s2 = fmaf(z2[0], w0.x, s2); s3 = fmaf(z3[0], w0.x, s3);
    s0 = fmaf(z0[1], w0.y, s0); s1 = fmaf(z1[1], w0.y, s1); s2 = fmaf(z2[1], w0.y, s2); s3 = fmaf(z3[1], w0.y, s3);
    s0 = fmaf(z0[2], w0.z, s0); s1 = fmaf(z1[2], w0.z, s1); s2 = fmaf(z2[2], w0.z, s2); s3 = fmaf(z3[2], w0.z, s3);
    s0 = fmaf(z0[3], w0.w, s0); s1 = fmaf(z1[3], w0.w, s1); s2 = fmaf(z2[3], w0.w, s2); s3 = fmaf(z3[3], w0.w, s3);
    s0 = fmaf(z0[4], w1.x, s0); s1 = fmaf(z1[4], w1.x, s1); s2 = fmaf(z2[4], w1.x, s2); s3 = fmaf(z3[4], w1.x, s3);
    s0 = fmaf(z0[5], w1.y, s0); s1 = fmaf(z1[5], w1.y, s1); s2 = fmaf(z2[5], w1.y, s2); s3 = fmaf(z3[5], w1.y, s3);
    s0 = fmaf(z0[6], w1.z, s0); s1 = fmaf(z1[6], w1.z, s1); s2 = fmaf(z2[6], w1.z, s2); s3 = fmaf(z3[6], w1.z, s3);
    s0 = fmaf(z0[7], w1.w, s0); s1 = fmaf(z1[7], w1.w, s1); s2 = fmaf(z2[7], w1.w, s2); s3 = fmaf(z3[7], w1.w, s3);
    *(float4*)&op[(size_t)o*TT] = make_float4(s0, s1, s2, s3);
  }
}

// ---------------- K4: loss finalize ----------------
__global__ void vq_k4_loss(const float* __restrict__ lpart, float* __restrict__ dout)
{
  const int b = threadIdx.x;
  if (b < NB) {
    float s = 0.f;
    for (int j = 0; j < NT2; ++j) s += lpart[b*NT2 + j];
    const float v = s / (float)(TT*DC);
    dout[OFF_CL + b] = v;
    dout[OFF_CB + b] = v;
  }
}

extern "C" void kernel_launch(void* const* d_in, const int* in_sizes, int n_in,
                              void* d_out, int out_size, void* d_ws, size_t ws_size,
                              hipStream_t stream) {
  const float* z     = (const float*)d_in[0];
  const float* in_w  = (const float*)d_in[1];
  const float* in_b  = (const float*)d_in[2];
  const float* out_w = (const float*)d_in[3];
  const float* out_b = (const float*)d_in[4];
  const float* cbk   = (const float*)d_in[5];
  float* out = (float*)d_out;
  float* ws  = (float*)d_ws;

  float* P  = ws;                                   // NDC*NB*DC*TT floats (8 MiB)
  float* ZQ = ws + (size_t)NDC*NB*DC*TT;            // NB*DC*TT floats (2 MiB)
  float* LP = ZQ + (size_t)NB*DC*TT;                // NB*NT2 floats

  vq_k1_inproj <<<dim3(NT1, NB, NDC), 256, 0, stream>>>(z, in_w, P);
  vq_k2_search <<<dim3(NT2, NB),      512, 0, stream>>>(P, in_b, cbk, out, ZQ, LP);
  vq_k3_outproj<<<dim3(NT3, NB, NOC), 256, 0, stream>>>(ZQ, out_w, out_b, out);
  vq_k4_loss   <<<1, 256, 0, stream>>>(LP, out);
}